// Round 2
// baseline (125.205 us; speedup 1.0000x reference)
//
#include <hip/hip_runtime.h>

#define B_ 4
#define T_ 512
#define C_ 128
#define NEG_INF_ (-1e22f)

// ---------------------------------------------------------------------------
// Kernel 1: q = x @ WQ, k = x @ WK (row-major, (B*T, C)) into workspace.
// grid 256 blocks (8 x-rows each), 256 threads. W staged in 32-row chunks.
// ---------------------------------------------------------------------------
__global__ __launch_bounds__(256) void qk_gemm(const float* __restrict__ x,
                                               const float* __restrict__ WQ,
                                               const float* __restrict__ WK,
                                               float* __restrict__ q,
                                               float* __restrict__ k) {
    __shared__ float xs[8][C_];        // 4 KB
    __shared__ float ws[2][32][C_];    // 32 KB
    const int tid = threadIdx.x;
    const int bid = blockIdx.x;
    const int b  = bid >> 6;
    const int t0 = (bid & 63) << 3;
    const size_t rowbase = ((size_t)b * T_ + t0) * C_;

    // stage 8 x-rows (coalesced)
    #pragma unroll
    for (int e = 0; e < 4; ++e) {
        int idx = e * 256 + tid;            // 0..1023
        int r = idx >> 7, c = idx & 127;
        xs[r][c] = x[rowbase + (size_t)r * C_ + c];
    }

    const int d = tid & 127;
    const int m = tid >> 7;                 // 0 = Q, 1 = K
    float acc[8];
    #pragma unroll
    for (int r = 0; r < 8; ++r) acc[r] = 0.f;

    for (int cc = 0; cc < 4; ++cc) {
        __syncthreads();
        // stage W chunk rows [cc*32, cc*32+32) of both matrices, float4
        #pragma unroll
        for (int it = 0; it < 8; ++it) {
            int idx = it * 256 + tid;       // 0..2047 float4 units
            int mm = idx >> 10;
            int r2 = idx & 1023;
            int cl = r2 >> 5;
            int dq = r2 & 31;
            const float* Wm = mm ? WK : WQ;
            float4 v = *(const float4*)&Wm[(size_t)(cc * 32 + cl) * C_ + dq * 4];
            *(float4*)&ws[mm][cl][dq * 4] = v;
        }
        __syncthreads();
        #pragma unroll
        for (int cl = 0; cl < 32; ++cl) {
            float w = ws[m][cl][d];         // lanes consecutive d: conflict-free
            #pragma unroll
            for (int r = 0; r < 8; ++r)
                acc[r] += xs[r][cc * 32 + cl] * w;   // xs broadcast
        }
    }
    float* o = m ? k : q;
    #pragma unroll
    for (int r = 0; r < 8; ++r)
        o[rowbase + (size_t)r * C_ + d] = acc[r];
}

// ---------------------------------------------------------------------------
// Kernel 2: fused score + mask + softmax + PV.
// grid = B * (T/8) = 256 blocks, 256 threads (4 waves) -> 1 block/CU.
// Block owns 8 i-rows. Thread tile: 4i x 4j scores.
//   ig = tid>>7 (i quad), jg = tid&127 (j quad) -> i = i0+ig*4+r, j = jg*4+c
// q[b] staged in LDS in 4 d-chunks [512 j][32 d], XOR-swizzled so b128
// staging writes and b128 score reads both run at the bank floor.
// Softmax: per-wave shfl_xor reduce + 2-wave LDS combine (row spans 2 waves).
// PV: att stays in registers, broadcast via v_readlane (VALU pipe, LDS idle);
// x read from global as float2 (L1/L2-resident). Normalization folded into
// the epilogue (out row /= rowsum).
// ---------------------------------------------------------------------------
__global__ __launch_bounds__(256) void lgcn_att(const float* __restrict__ x,
                                                const float* __restrict__ adj,
                                                const float* __restrict__ q,
                                                const float* __restrict__ k,
                                                const float* __restrict__ p,
                                                float* __restrict__ out) {
    __shared__ float qs[512 * 32];     // 64 KB, swizzled chunk
    __shared__ float ks[8][C_];        // 4 KB
    __shared__ float ps[C_];           // 0.5 KB
    __shared__ float outp[4][4][C_];   // 8 KB per-wave PV partials
    __shared__ float redm[4][4];
    __shared__ float reds[4][4];

    const int tid  = threadIdx.x;
    const int bid  = blockIdx.x;
    const int b    = bid >> 6;
    const int i0   = (bid & 63) << 3;
    const int ig   = tid >> 7;         // 0..1
    const int jg   = tid & 127;        // 0..127
    const int lane = tid & 63;
    const int wv   = tid >> 6;         // wave 0..3
    const int jh   = (tid >> 6) & 1;   // j-half within ig group

    // stage k rows (8 x 128) and p
    #pragma unroll
    for (int e = 0; e < 4; ++e) {
        int idx = e * 256 + tid;
        int ii = idx >> 7, d = idx & 127;
        ks[ii][d] = k[((size_t)b * T_ + i0 + ii) * C_ + d];
    }
    if (tid < C_) ps[tid] = p[tid];

    float s[4][4];
    #pragma unroll
    for (int r = 0; r < 4; ++r)
        #pragma unroll
        for (int c = 0; c < 4; ++c) s[r][c] = 0.f;

    const float* qb = q + (size_t)b * T_ * C_;
    for (int cd = 0; cd < 4; ++cd) {
        __syncthreads();
        // stage q chunk: all 512 j, d in [cd*32, cd*32+32), swizzled
        #pragma unroll
        for (int it = 0; it < 16; ++it) {
            int idx = it * 256 + tid;      // 0..4095 float4 units
            int j = idx >> 3, dq = idx & 7;
            float4 v = *(const float4*)&qb[(size_t)j * C_ + cd * 32 + dq * 4];
            int off = (j * 128 + dq * 16) ^ (((j >> 2) & 7) << 4);  // bytes
            *(float4*)((char*)qs + off) = v;
        }
        __syncthreads();

        // hoist this chunk's p segment (8 float4, reused across all dl)
        float4 pch[8];
        #pragma unroll
        for (int e = 0; e < 8; ++e)
            pch[e] = *(const float4*)&ps[cd * 32 + e * 4];

        #pragma unroll
        for (int dl = 0; dl < 32; dl += 4) {
            float4 pv = pch[dl >> 2];
            float4 kv[4], qv[4];
            #pragma unroll
            for (int r = 0; r < 4; ++r)    // wave-uniform: LDS broadcast
                kv[r] = *(const float4*)&ks[ig * 4 + r][cd * 32 + dl];
            #pragma unroll
            for (int c = 0; c < 4; ++c) {
                int j = jg * 4 + c;
                int off = (j * 128 + dl * 4) ^ (((j >> 2) & 7) << 4);
                qv[c] = *(const float4*)((char*)qs + off);
            }
            #pragma unroll
            for (int r = 0; r < 4; ++r) {
                #pragma unroll
                for (int c = 0; c < 4; ++c) {
                    s[r][c] += pv.x * fmaxf(qv[c].x + kv[r].x, 0.f);
                    s[r][c] += pv.y * fmaxf(qv[c].y + kv[r].y, 0.f);
                    s[r][c] += pv.z * fmaxf(qv[c].z + kv[r].z, 0.f);
                    s[r][c] += pv.w * fmaxf(qv[c].w + kv[r].w, 0.f);
                }
            }
        }
    }

    // mask: score stays if adj > 0 else exactly -1e22 (matches fp32 ref:
    // score-1e22 rounds to -1e22, exp underflows to 0 either way)
    const float* adjb = adj + ((size_t)b * T_ + i0) * T_;
    #pragma unroll
    for (int r = 0; r < 4; ++r) {
        float4 a4 = *(const float4*)&adjb[(size_t)(ig * 4 + r) * T_ + jg * 4];
        s[r][0] = (a4.x > 0.f) ? s[r][0] : NEG_INF_;
        s[r][1] = (a4.y > 0.f) ? s[r][1] : NEG_INF_;
        s[r][2] = (a4.z > 0.f) ? s[r][2] : NEG_INF_;
        s[r][3] = (a4.w > 0.f) ? s[r][3] : NEG_INF_;
    }

    // row max (row spans 128 threads = 2 waves)
    float m4[4];
    #pragma unroll
    for (int r = 0; r < 4; ++r) {
        float mv = fmaxf(fmaxf(s[r][0], s[r][1]), fmaxf(s[r][2], s[r][3]));
        #pragma unroll
        for (int o = 32; o > 0; o >>= 1)
            mv = fmaxf(mv, __shfl_xor(mv, o, 64));
        m4[r] = mv;
    }
    if (lane == 0) {
        #pragma unroll
        for (int r = 0; r < 4; ++r) redm[wv][r] = m4[r];
    }
    __syncthreads();
    float rowmax[4];
    #pragma unroll
    for (int r = 0; r < 4; ++r)
        rowmax[r] = fmaxf(redm[ig * 2][r], redm[ig * 2 + 1][r]);

    // exp (unnormalized) + row sum
    float e_[4][4];
    float sum4[4];
    #pragma unroll
    for (int r = 0; r < 4; ++r) {
        float sm = 0.f;
        #pragma unroll
        for (int c = 0; c < 4; ++c) {
            float ev = __expf(s[r][c] - rowmax[r]);
            e_[r][c] = ev;
            sm += ev;
        }
        #pragma unroll
        for (int o = 32; o > 0; o >>= 1)
            sm += __shfl_xor(sm, o, 64);
        sum4[r] = sm;
    }
    if (lane == 0) {
        #pragma unroll
        for (int r = 0; r < 4; ++r) reds[wv][r] = sum4[r];
    }
    __syncthreads();
    float inv[4];
    #pragma unroll
    for (int r = 0; r < 4; ++r)
        inv[r] = 1.0f / (reds[ig * 2][r] + reds[ig * 2 + 1][r]);

    // PV: wave handles its 256 j's; att broadcast from registers via readlane.
    // lane owns d = {2*lane, 2*lane+1}; acc[r] is the 4-row partial.
    const float2* xb2 = (const float2*)(x + (size_t)b * T_ * C_);
    float2 acc[4];
    #pragma unroll
    for (int r = 0; r < 4; ++r) acc[r] = make_float2(0.f, 0.f);
    const int jbase = jh * 256;
    #pragma unroll 2
    for (int l = 0; l < 64; ++l) {
        // batch the 4 x-loads ahead of the fma chain (latency hiding at
        // 1 wave/SIMD)
        float2 xv[4];
        #pragma unroll
        for (int c = 0; c < 4; ++c) {
            int j = jbase + 4 * l + c;
            xv[c] = xb2[(size_t)j * 64 + lane];
        }
        #pragma unroll
        for (int c = 0; c < 4; ++c) {
            #pragma unroll
            for (int r = 0; r < 4; ++r) {
                float a = __int_as_float(
                    __builtin_amdgcn_readlane(__float_as_int(e_[r][c]), l));
                acc[r].x += a * xv[c].x;
                acc[r].y += a * xv[c].y;
            }
        }
    }
    #pragma unroll
    for (int r = 0; r < 4; ++r)
        *(float2*)&outp[wv][r][lane * 2] = acc[r];
    __syncthreads();

    // combine j-halves, normalize, write out (coalesced)
    const int d = tid & 127;
    #pragma unroll
    for (int r = 0; r < 4; ++r) {
        float v = (outp[ig * 2][r][d] + outp[ig * 2 + 1][r][d]) * inv[r];
        out[((size_t)b * T_ + i0 + ig * 4 + r) * C_ + d] = v;
    }
}

extern "C" void kernel_launch(void* const* d_in, const int* in_sizes, int n_in,
                              void* d_out, int out_size, void* d_ws, size_t ws_size,
                              hipStream_t stream) {
    const float* x   = (const float*)d_in[0];
    const float* adj = (const float*)d_in[1];
    const float* WQ  = (const float*)d_in[2];
    const float* WK  = (const float*)d_in[3];
    const float* p   = (const float*)d_in[4];
    float* outp = (float*)d_out;

    float* q = (float*)d_ws;                       // 1 MB
    float* k = q + (size_t)B_ * T_ * C_;           // 1 MB
    (void)ws_size; (void)in_sizes; (void)n_in;

    qk_gemm<<<256, 256, 0, stream>>>(x, WQ, WK, q, k);
    lgcn_att<<<256, 256, 0, stream>>>(x, adj, q, k, p, outp);
}